// Round 9
// baseline (316.911 us; speedup 1.0000x reference)
//
#include <hip/hip_runtime.h>
#include <hip/hip_bf16.h>

// ---------- types ----------
typedef __attribute__((ext_vector_type(8))) short short8;   // 8 bf16 (4 VGPR)
typedef __attribute__((ext_vector_type(4))) short short4v;  // 4 bf16
typedef __attribute__((ext_vector_type(4))) float f32x4;

#define D_IN   2048
#define D_OUT  1024

__device__ __forceinline__ short f2bf(float x) {
    union { __hip_bfloat16 h; short s; } u;
    u.h = __float2bfloat16(x);
    return u.s;
}

// ---------- 1. W [2048][1024] f32 -> Bt [1024][2048] bf16 ----------
__global__ void transpose_w_kernel(const float* __restrict__ W,
                                   short* __restrict__ Bt) {
    __shared__ float tile[32][33];
    int c0 = blockIdx.x * 32;
    int r0 = blockIdx.y * 32;
    int tc = threadIdx.x & 31;
    int tr = threadIdx.x >> 5;
#pragma unroll
    for (int i = 0; i < 32; i += 8)
        tile[tr + i][tc] = W[(long)(r0 + tr + i) * D_OUT + c0 + tc];
    __syncthreads();
#pragma unroll
    for (int i = 0; i < 32; i += 8)
        Bt[(long)(c0 + tr + i) * D_IN + r0 + tc] = f2bf(tile[tc][tr + i]);
}

// ---------- 2. Fully-fused: GEMM(64x1024x2048) + bias + ReLU + LN + pack ----------
// One block = one image, 8 waves; wave w owns cols [w*128, +128). BK=32.
// B: NO LDS — fragments read direct Bt->VGPR (L2-resident 4 MiB panel),
//    one-tile register ping-pong bA/bB.
// A: reg-staged f32->bf16 into a single-buffered 4 KiB LDS tile
//    ([64 rows][64 B], atom swizzle slot = chunk ^ (r&3) ^ ((r>>2)&3)),
//    2 barriers/tile. LDS traffic 36 KiB/tile << MFMA floor per tile.

#define BAR()    __builtin_amdgcn_s_barrier()
#define SB0()    __builtin_amdgcn_sched_barrier(0)
#define LGKM0()  do { asm volatile("s_waitcnt lgkmcnt(0)" ::: "memory"); SB0(); } while (0)

__global__ __launch_bounds__(512, 2)
void fused_kernel(const float* __restrict__ img, const short* __restrict__ Bt,
                  const float* __restrict__ bias, const int* __restrict__ mask,
                  const float* __restrict__ lnw, const float* __restrict__ lnb,
                  float* __restrict__ out) {
    __shared__ char LDS[8192];     // A tile 4 KiB + epilogue scratch (4.5 KiB)

    const int b    = blockIdx.x;
    const int tid  = threadIdx.x;
    const int lane = tid & 63;
    const int w    = tid >> 6;
    const int lrow = lane & 15;
    const int lchk = lane >> 4;    // k-chunk 0..3

    // A staging: row arl = tid>>3, 4 f32 k-elems at (tid&7)*4; half-atom write.
    const int arl   = tid >> 3;
    const long arowg = (long)b * 64 + arl;
    const int ak4   = (tid & 7) * 4;
    const int achk  = (tid & 7) >> 1;
    char* adst = LDS + arl * 64
               + ((achk ^ (arl & 3) ^ ((arl >> 2) & 3)) * 16) + (tid & 1) * 8;
    // A frag-read base (swizzle mi-independent: +1024 never touches bits 4..5)
    const int fsw = ((lchk ^ (lrow & 3) ^ ((lrow >> 2) & 3)) << 4);
    const char* afb = LDS + lrow * 64 + fsw;

    // B direct per-lane base: col = w*128 + nf*16 + lrow, 16B at k = t*32+lchk*8
    const short* bsrc = Bt + (long)(w * 128 + lrow) * D_IN + lchk * 8;

    f32x4 acc[4][8];
#pragma unroll
    for (int i = 0; i < 4; ++i)
#pragma unroll
        for (int j = 0; j < 8; ++j) acc[i][j] = (f32x4)0.0f;

    float4 stA;
    short8 bA[8], bB[8], fa[4];

#define A_WRITE() do {                                                          \
    short4v ca;                                                                 \
    ca[0] = f2bf(stA.x); ca[1] = f2bf(stA.y);                                   \
    ca[2] = f2bf(stA.z); ca[3] = f2bf(stA.w);                                   \
    *(short4v*)adst = ca;                                                       \
} while (0)
#define FA_READ() do {                                                          \
    _Pragma("unroll") for (int mi = 0; mi < 4; ++mi)                            \
        fa[mi] = *(const short8*)(afb + mi * 1024);                             \
} while (0)
#define B_LOAD(dst, kt) do {                                                    \
    _Pragma("unroll") for (int nf = 0; nf < 8; ++nf)                            \
        dst[nf] = *(const short8*)(bsrc + (long)nf * 16 * D_IN + (kt) * 32);    \
} while (0)
#define MFMA_T(fb) do {                                                         \
    __builtin_amdgcn_s_setprio(1);                                              \
    _Pragma("unroll") for (int mi = 0; mi < 4; ++mi)                            \
    _Pragma("unroll") for (int nf = 0; nf < 8; ++nf)                            \
        acc[mi][nf] = __builtin_amdgcn_mfma_f32_16x16x32_bf16(                  \
            fa[mi], fb[nf], acc[mi][nf], 0, 0, 0);                              \
    __builtin_amdgcn_s_setprio(0);                                              \
} while (0)

    // ---- prologue: tile-0 A f32 + tile-0 B frags in flight
    stA = *(const float4*)(img + arowg * D_IN + ak4);
    B_LOAD(bA, 0);

#pragma unroll 1
    for (int t = 0; t < 64; t += 2) {
        // ---- even tile t: consume bA; load bB(t+1)
        BAR(); SB0();                      // A(t-1) frag reads consumed by all waves
        A_WRITE();                         // compiler vmcnt waits stA only
        stA = *(const float4*)(img + arowg * D_IN + (t + 1) * 32 + ak4);
        LGKM0(); BAR(); SB0();             // A(t) published
        FA_READ();
        B_LOAD(bB, t + 1);
        MFMA_T(bA);                        // waits lgkm(fa) + vmcnt(bA, 1 tile old)

        // ---- odd tile t+1: consume bB; load bA(t+2)
        BAR(); SB0();
        A_WRITE();
        {   // FIXED (R8 bug): wrap the TILE index, keep *32 + ak4.
            int k2 = ((t + 2) & 63) * 32;  // t=62 -> in-range junk, never consumed
            stA = *(const float4*)(img + arowg * D_IN + k2 + ak4);
        }
        LGKM0(); BAR(); SB0();
        FA_READ();
        B_LOAD(bA, (t + 2) & 63);          // junk at t=62, never consumed
        MFMA_T(bB);
    }

    // ---- epilogue: bias+ReLU, LN stats, mask-pack, store (R6/R7-verified)
    __syncthreads();

    float* redS = (float*)LDS;             // [8][64]
    float* redQ = (float*)(LDS + 2048);    // [8][64]
    float* muT  = (float*)(LDS + 4096);    // [64]
    float* rsT  = (float*)(LDS + 4352);    // [64]

    float bb[8];
#pragma unroll
    for (int nf = 0; nf < 8; ++nf) bb[nf] = bias[w * 128 + nf * 16 + lrow];

    float s[4][4], q[4][4];
#pragma unroll
    for (int mi = 0; mi < 4; ++mi)
#pragma unroll
        for (int r = 0; r < 4; ++r) { s[mi][r] = 0.f; q[mi][r] = 0.f; }
#pragma unroll
    for (int mi = 0; mi < 4; ++mi)
#pragma unroll
        for (int nf = 0; nf < 8; ++nf)
#pragma unroll
            for (int r = 0; r < 4; ++r) {
                float v = fmaxf(acc[mi][nf][r] + bb[nf], 0.f);
                acc[mi][nf][r] = v;
                s[mi][r] += v;
                q[mi][r] += v * v;
            }
#pragma unroll
    for (int mi = 0; mi < 4; ++mi)
#pragma unroll
        for (int r = 0; r < 4; ++r)
#pragma unroll
            for (int off = 1; off <= 8; off <<= 1) {
                s[mi][r] += __shfl_xor(s[mi][r], off);
                q[mi][r] += __shfl_xor(q[mi][r], off);
            }
    if (lrow == 0) {
#pragma unroll
        for (int mi = 0; mi < 4; ++mi)
#pragma unroll
            for (int r = 0; r < 4; ++r) {
                int m = mi * 16 + lchk * 4 + r;
                redS[w * 64 + m] = s[mi][r];
                redQ[w * 64 + m] = q[mi][r];
            }
    }
    __syncthreads();
    if (tid < 64) {
        float S = 0.f, Q = 0.f;
#pragma unroll
        for (int ww = 0; ww < 8; ++ww) { S += redS[ww * 64 + tid]; Q += redQ[ww * 64 + tid]; }
        float mu  = S * (1.0f / 1024.0f);
        float var = Q * (1.0f / 1024.0f) - mu * mu;
        muT[tid] = mu;
        rsT[tid] = rsqrtf(var + 1e-12f);
    }
    __syncthreads();

    int mv = mask[(b << 6) | lane];
    unsigned long long bal = __ballot(mv != 0);
    int cnt = __popcll(bal);

    float lw[8], lb[8];
#pragma unroll
    for (int nf = 0; nf < 8; ++nf) {
        int col = w * 128 + nf * 16 + lrow;
        lw[nf] = lnw[col];
        lb[nf] = lnb[col];
    }
#pragma unroll
    for (int mi = 0; mi < 4; ++mi)
#pragma unroll
        for (int r = 0; r < 4; ++r) {
            int m = mi * 16 + lchk * 4 + r;
            if ((bal >> m) & 1ull) {
                int d = __popcll(bal & ((1ull << m) - 1ull));
                float mu = muT[m], rs = rsT[m];
                long obase = ((long)(b << 6) + d) * D_OUT + w * 128 + lrow;
#pragma unroll
                for (int nf = 0; nf < 8; ++nf)
                    out[obase + nf * 16] = (acc[mi][nf][r] - mu) * rs * lw[nf] + lb[nf];
            }
        }
    // zero the padded tail rows (deterministic full coverage of d_out)
    for (int d = cnt; d < 64; ++d) {
        float2 z = make_float2(0.f, 0.f);
        *(float2*)(out + ((long)(b << 6) + d) * D_OUT + w * 128 + lane * 2) = z;
    }
}

// ---------- launch ----------
extern "C" void kernel_launch(void* const* d_in, const int* in_sizes, int n_in,
                              void* d_out, int out_size, void* d_ws, size_t ws_size,
                              hipStream_t stream) {
    const float* img  = (const float*)d_in[0];
    const int*   mask = (const int*)d_in[2];
    const float* W    = (const float*)d_in[4];
    const float* bias = (const float*)d_in[5];
    const float* lnw  = (const float*)d_in[6];
    const float* lnb  = (const float*)d_in[7];
    float* out = (float*)d_out;

    short* Bt = (short*)d_ws;   // 4 MiB

    transpose_w_kernel<<<dim3(D_OUT / 32, D_IN / 32), 256, 0, stream>>>(W, Bt);
    fused_kernel<<<512, 512, 0, stream>>>(img, Bt, bias, mask, lnw, lnb, out);
}